// Round 12
// baseline (234.872 us; speedup 1.0000x reference)
//
#include <hip/hip_runtime.h>
#include <cstdint>

#define TOKENS 16384   // b*l = 4*4096
#define DIM 1024
#define NW 3072        // GEMM1 N: q-slots0-63 (1024) | k (1024) | v (1024) = 12 x 256
#define NKT 16         // K = 1024 = 16 K-tiles of 64

typedef __bf16 bf16_t;
typedef bf16_t bf16x8 __attribute__((ext_vector_type(8)));
typedef unsigned short u16x8 __attribute__((ext_vector_type(8)));
typedef float f32x4 __attribute__((ext_vector_type(4)));

static __device__ __forceinline__ float bf2f(unsigned short u) {
    union { unsigned int i; float f; } v; v.i = ((unsigned int)u) << 16; return v.f;
}
static __device__ __forceinline__ unsigned short f2bf(float f) {
    unsigned int u = __float_as_uint(f);
    unsigned int r = u + 0x7FFFu + ((u >> 16) & 1u);   // RNE
    return (unsigned short)(r >> 16);
}

// async global->LDS, 16B/lane; LDS dest is wave-uniform base + lane*16B (linear).
static __device__ __forceinline__ void gload_lds16(const void* g, void* l) {
    __builtin_amdgcn_global_load_lds(
        (__attribute__((address_space(1))) void*)(uintptr_t)g,
        (__attribute__((address_space(3))) void*)(unsigned int)(uintptr_t)l,
        16, 0, 0);
}

// ---------------- merged cast kernel ----------------
// Blocks [0, TOKENS/4): one WAVE per token — cast x row f32->bf16 AND compute the 16
//   per-head slot-64 q logits q64[t][h] = dot(x_row_bf16, Wq[h*65+64] f32) (r12: moved
//   here from gate; VALU hides under the cast's BW time).
// Blocks [TOKENS/4, +4096): weights — Wall[3072][1024] (q slots0-63 | k | v) and Wo.
#define XBLKS  (TOKENS / 4)                 // 4096
#define WALLN4 (NW * DIM / 4)               //   786,432
#define WON4   (DIM * DIM / 4)              //   262,144
#define WBLKS  ((WALLN4 + WON4) / 256)      // 4096
__global__ __launch_bounds__(256) void k_cast_all(const float* __restrict__ x,
                                                  const float* __restrict__ Wq,
                                                  const float* __restrict__ Wk,
                                                  const float* __restrict__ Wv,
                                                  const float* __restrict__ Wo,
                                                  unsigned short* __restrict__ xb,
                                                  unsigned short* __restrict__ Wall,
                                                  unsigned short* __restrict__ Wob,
                                                  float* __restrict__ q64) {
    const int b = blockIdx.x;
    if (b < XBLKS) {
        const int t    = b * 4 + (threadIdx.x >> 6);
        const int lane = threadIdx.x & 63;
        const float4* xsrc = (const float4*)(x + (size_t)t * DIM + lane * 16);
        float vals[16];
        unsigned short us[16];
#pragma unroll
        for (int q = 0; q < 4; ++q) {
            const float4 v = xsrc[q];
            us[q * 4 + 0] = f2bf(v.x); us[q * 4 + 1] = f2bf(v.y);
            us[q * 4 + 2] = f2bf(v.z); us[q * 4 + 3] = f2bf(v.w);
        }
#pragma unroll
        for (int j = 0; j < 16; ++j) vals[j] = bf2f(us[j]);   // bf16-rounded x (matches GEMM input)
        u16x8 o0, o1;
#pragma unroll
        for (int j = 0; j < 8; ++j) { o0[j] = us[j]; o1[j] = us[8 + j]; }
        *(u16x8*)(xb + (size_t)t * DIM + lane * 16)     = o0;
        *(u16x8*)(xb + (size_t)t * DIM + lane * 16 + 8) = o1;
        // q64 dots (Wq slot-64 rows read as raw f32; L2-resident)
#pragma unroll
        for (int h = 0; h < 16; ++h) {
            const float4* wsrc = (const float4*)(Wq + ((size_t)h * 65 + 64) * DIM + lane * 16);
            float d = 0.f;
#pragma unroll
            for (int q = 0; q < 4; ++q) {
                const float4 w = wsrc[q];
                d += vals[q * 4 + 0] * w.x + vals[q * 4 + 1] * w.y
                   + vals[q * 4 + 2] * w.z + vals[q * 4 + 3] * w.w;
            }
            for (int o = 32; o; o >>= 1) d += __shfl_xor(d, o);
            if (lane == 0) q64[(size_t)t * 16 + h] = d;
        }
    } else {
        const int j = (b - XBLKS) * 256 + threadIdx.x;   // over WALLN4 + WON4
        float4 v;
        unsigned short* dst;
        if (j < WALLN4) {
            const int c4 = j & 255;          // DIM/4 = 256
            const int r  = j >> 8;
            if (r < 1024)      v = ((const float4*)Wq)[((r >> 6) * 65 + (r & 63)) * 256 + c4];
            else if (r < 2048) v = ((const float4*)Wk)[(r - 1024) * 256 + c4];
            else               v = ((const float4*)Wv)[(r - 2048) * 256 + c4];
            dst = Wall + (size_t)j * 4;
        } else {
            const int jj = j - WALLN4;
            v = ((const float4*)Wo)[jj];
            dst = Wob + (size_t)jj * 4;
        }
        ushort4 o;
        o.x = f2bf(v.x); o.y = f2bf(v.y); o.z = f2bf(v.z); o.w = f2bf(v.w);
        *(ushort4*)dst = o;
    }
}

// ============ 256x256x(BK=64) 8-phase bf16 GEMM: C[M,N] = A[M,K] * Bt[N,K]^T ============
// UNIFORM epilogue — the ONLY stable config (r5/r9/r10: ~107 µs / 94 MB FETCH).
// Any per-kind epilogue divergence costs +60 MB L2 refetch (r6/r8/r11 all refuted).
template<int ADD_BIAS, int OUT_F32>
__global__ __launch_bounds__(512, 2) void k_gemm256(const unsigned short* __restrict__ A, int lda,
                                                    const unsigned short* __restrict__ Bt, int ldb,
                                                    void* __restrict__ Cout, int ldc,
                                                    const float* __restrict__ bias) {
    __shared__ char smem[131072];
    const int tid  = threadIdx.x;
    const int wid  = tid >> 6;          // 0..7
    const int lane = tid & 63;
    const int wm = wid >> 2;            // 0..1  (M half)
    const int wn = wid & 3;             // 0..3  (N quarter)
    const int fr = lane & 15;
    const int fq = lane >> 4;
    const int fr7 = fr & 7;
    const int srow8  = lane >> 3;                        // staging row-in-chunk
    const int cperm8 = ((lane & 7) ^ srow8) * 8;         // staging col perm (elements)

    // XCD-chunked bijective swizzle (nb divisible by 8 for both GEMMs)
    const int nbx = gridDim.x;
    const int nb  = nbx * gridDim.y;
    const int L   = blockIdx.y * nbx + blockIdx.x;
    const int q8  = nb >> 3;
    const int newid = (L & 7) * q8 + (L >> 3);
    const int tm = (newid / nbx) * 256;
    const int tn = (newid % nbx) * 256;

#define STAGE(ptr, ld, tile0, kt2, h, matbase)                                              \
    {                                                                                        \
        _Pragma("unroll")                                                                    \
        for (int j = 0; j < 2; ++j) {                                                        \
            const int c = wid * 2 + j;                                                       \
            const unsigned short* src = (ptr) +                                              \
                (size_t)((tile0) + (h) * 128 + c * 8 + srow8) * (ld) + (kt2) * 64 + cperm8;  \
            char* dst = (char*)smem + ((((kt2) & 1) << 16) | (matbase) | ((h) << 14) | (c << 10)); \
            gload_lds16(src, dst);                                                           \
        }                                                                                    \
    }
#define STAGE_A(kt2, h) STAGE(A, lda, tm, kt2, h, 0)
#define STAGE_B(kt2, h) STAGE(Bt, ldb, tn, kt2, h, 32768)

    const int sx0 = ((0 + fq) ^ fr7) << 4;              // ks=0 16B slot (swizzled)
    const int sx1 = ((4 + fq) ^ fr7) << 4;              // ks=1
    const int aoff = (wm << 14) + (fr << 7);
    const int boff = 32768 + ((wn >> 1) << 14) + ((((wn & 1) * 64) + fr) << 7);

    bf16x8 a[4][2], b0[2][2], b1[2][2];
    f32x4 acc[8][4] = {};

#define READ_A(kb, mh)                                                                       \
    { _Pragma("unroll")                                                                      \
      for (int i = 0; i < 4; ++i) {                                                          \
        a[i][0] = *(const bf16x8*)(smem + (kb) + aoff + (((mh) * 64 + i * 16) << 7) + sx0);  \
        a[i][1] = *(const bf16x8*)(smem + (kb) + aoff + (((mh) * 64 + i * 16) << 7) + sx1);  \
      } }
#define READ_B(kb, nh, breg)                                                                 \
    { _Pragma("unroll")                                                                      \
      for (int n2 = 0; n2 < 2; ++n2) {                                                       \
        breg[n2][0] = *(const bf16x8*)(smem + (kb) + boff + ((((nh) * 2 + n2) * 16) << 7) + sx0); \
        breg[n2][1] = *(const bf16x8*)(smem + (kb) + boff + ((((nh) * 2 + n2) * 16) << 7) + sx1); \
      } }
#define MFMA_Q(mh, nh, breg)                                                                 \
    { _Pragma("unroll")                                                                      \
      for (int i = 0; i < 4; ++i)                                                            \
        _Pragma("unroll")                                                                    \
        for (int n2 = 0; n2 < 2; ++n2) {                                                     \
          acc[(mh) * 4 + i][(nh) * 2 + n2] = __builtin_amdgcn_mfma_f32_16x16x32_bf16(        \
              a[i][0], breg[n2][0], acc[(mh) * 4 + i][(nh) * 2 + n2], 0, 0, 0);              \
          acc[(mh) * 4 + i][(nh) * 2 + n2] = __builtin_amdgcn_mfma_f32_16x16x32_bf16(        \
              a[i][1], breg[n2][1], acc[(mh) * 4 + i][(nh) * 2 + n2], 0, 0, 0);              \
        } }
#define SYNC_PRE()                                             \
    __builtin_amdgcn_s_barrier();                              \
    asm volatile("s_waitcnt lgkmcnt(0)" ::: "memory");         \
    __builtin_amdgcn_sched_barrier(0);                         \
    __builtin_amdgcn_s_setprio(1);
#define SYNC_POST()                                            \
    __builtin_amdgcn_s_setprio(0);                             \
    __builtin_amdgcn_s_barrier();

    // ---- prologue: kt0 fully + kt1's B halves; drain the kt0 stages ----
    STAGE_A(0, 0); STAGE_A(0, 1); STAGE_B(0, 0); STAGE_B(0, 1);
    STAGE_B(1, 0); STAGE_B(1, 1);
    asm volatile("s_waitcnt vmcnt(4)" ::: "memory");
    __builtin_amdgcn_s_barrier();

    for (int kt = 0; kt < NKT; ++kt) {
        const int kb = (kt & 1) << 16;
        // ---- P0 ----
        READ_A(kb, 0);
        READ_B(kb, 0, b0);
        if (kt < NKT - 1) STAGE_A(kt + 1, 0);
        asm volatile("s_waitcnt lgkmcnt(8)" ::: "memory");
        SYNC_PRE(); MFMA_Q(0, 0, b0); SYNC_POST();
        // ---- P1 ----
        READ_B(kb, 1, b1);
        if (kt < NKT - 1) STAGE_A(kt + 1, 1);
        SYNC_PRE(); MFMA_Q(0, 1, b1); SYNC_POST();
        // ---- P2 ----
        READ_A(kb, 1);
        if (kt < NKT - 2) STAGE_B(kt + 2, 0);
        SYNC_PRE(); MFMA_Q(1, 1, b1); SYNC_POST();
        // ---- P3 (no ds_read; uses regs a[mh1], b0) ----
        if (kt < NKT - 2) STAGE_B(kt + 2, 1);
        __builtin_amdgcn_s_barrier();
        __builtin_amdgcn_s_setprio(1); MFMA_Q(1, 0, b0); __builtin_amdgcn_s_setprio(0);
        if (kt < NKT - 2) { asm volatile("s_waitcnt vmcnt(4)" ::: "memory"); }
        else              { asm volatile("s_waitcnt vmcnt(0)" ::: "memory"); }
        __builtin_amdgcn_s_barrier();
    }

    // ---- epilogue: uniform C write ----
#pragma unroll
    for (int mq = 0; mq < 8; ++mq) {
        const int row0 = tm + wm * 128 + mq * 16 + fq * 4;
#pragma unroll
        for (int nf = 0; nf < 4; ++nf) {
            const int col = tn + wn * 64 + nf * 16 + fr;
            f32x4 v = acc[mq][nf];
            const float bb = ADD_BIAS ? bias[col] : 0.0f;
#pragma unroll
            for (int j = 0; j < 4; ++j) {
                const size_t idx = (size_t)(row0 + j) * ldc + col;
                if (OUT_F32) ((float*)Cout)[idx] = v[j] + bb;
                else         ((unsigned short*)Cout)[idx] = f2bf(v[j] + bb);
            }
        }
    }
#undef STAGE
#undef STAGE_A
#undef STAGE_B
#undef READ_A
#undef READ_B
#undef MFMA_Q
#undef SYNC_PRE
#undef SYNC_POST
}

// -------- gate: ONE WAVE PER TOKEN; lane owns 16 consecutive slots, head = aligned
// 4-lane group (reduces = shfl_xor 1,2). q-softmax -> wf (q64 from the cast kernel's
// buffer), k-softmax -> ksm, v-gate, all in-register; C1 row = [q|k|v], v in place. ----
__global__ __launch_bounds__(256) void k_gate(unsigned short* __restrict__ C1,
                                              const float* __restrict__ q64,
                                              const float* __restrict__ mask) {
    const int t    = blockIdx.x * 4 + (threadIdx.x >> 6);
    const int lane = threadIdx.x & 63;
    const int h    = lane >> 2;
    unsigned short* row = C1 + (size_t)t * NW;
    const float mk = mask[t];

    // ---- q softmax (64 slots per head across 4 lanes, 16/lane) ----
    const u16x8 q0 = *(const u16x8*)(row + lane * 16);
    const u16x8 q1 = *(const u16x8*)(row + lane * 16 + 8);
    float qf[16];
#pragma unroll
    for (int j = 0; j < 8; ++j) { qf[j] = bf2f(q0[j]); qf[8 + j] = bf2f(q1[j]); }
    float mx = qf[0];
#pragma unroll
    for (int j = 1; j < 16; ++j) mx = fmaxf(mx, qf[j]);
    mx = fmaxf(mx, __shfl_xor(mx, 1));
    mx = fmaxf(mx, __shfl_xor(mx, 2));
    float sm = 0.f;
#pragma unroll
    for (int j = 0; j < 16; ++j) sm += __expf(qf[j] - mx);
    sm += __shfl_xor(sm, 1);
    sm += __shfl_xor(sm, 2);
    const float e64 = __expf(q64[(size_t)t * 16 + h] - mx);
    const float wf = 2.0f * (1.0f - e64 / (sm + e64)) * mk;

    // ---- k softmax ----
    const u16x8 k0 = *(const u16x8*)(row + 1024 + lane * 16);
    const u16x8 k1 = *(const u16x8*)(row + 1024 + lane * 16 + 8);
    float ek[16];
    {
        float kf[16];
#pragma unroll
        for (int j = 0; j < 8; ++j) { kf[j] = bf2f(k0[j]); kf[8 + j] = bf2f(k1[j]); }
        float kmx = kf[0];
#pragma unroll
        for (int j = 1; j < 16; ++j) kmx = fmaxf(kmx, kf[j]);
        kmx = fmaxf(kmx, __shfl_xor(kmx, 1));
        kmx = fmaxf(kmx, __shfl_xor(kmx, 2));
#pragma unroll
        for (int j = 0; j < 16; ++j) ek[j] = __expf(kf[j] - kmx);
    }
    float ks = 0.f;
#pragma unroll
    for (int j = 0; j < 16; ++j) ks += ek[j];
    ks += __shfl_xor(ks, 1);
    ks += __shfl_xor(ks, 2);
    const float f = wf / ks;   // wf * (1/ks); per-slot ksm = ek[j] * (1/ks)

    // ---- gate v in place ----
    const u16x8 v0 = *(const u16x8*)(row + 2048 + lane * 16);
    const u16x8 v1 = *(const u16x8*)(row + 2048 + lane * 16 + 8);
    u16x8 o0, o1;
#pragma unroll
    for (int j = 0; j < 8; ++j) {
        o0[j] = f2bf(f * ek[j]     * bf2f(v0[j]));
        o1[j] = f2bf(f * ek[8 + j] * bf2f(v1[j]));
    }
    *(u16x8*)(row + 2048 + lane * 16)     = o0;
    *(u16x8*)(row + 2048 + lane * 16 + 8) = o1;
}

extern "C" void kernel_launch(void* const* d_in, const int* in_sizes, int n_in,
                              void* d_out, int out_size, void* d_ws, size_t ws_size,
                              hipStream_t stream) {
    (void)in_sizes; (void)n_in; (void)out_size; (void)ws_size;
    const float* x  = (const float*)d_in[0];
    const float* am = (const float*)d_in[1];
    const float* Wq = (const float*)d_in[2];
    const float* Wk = (const float*)d_in[3];
    const float* Wv = (const float*)d_in[4];
    const float* Wo = (const float*)d_in[5];
    const float* bo = (const float*)d_in[6];
    // time_angle / head_time_delta collapse to the constant 2 (see round-0 analysis)

    char* ws = (char*)d_ws;
    unsigned short* xb   = (unsigned short*)(ws);                  // 16384x1024 bf16   33,554,432 B
    unsigned short* Wall = (unsigned short*)(ws + 33554432);       // 3072x1024 bf16     6,291,456 B
    unsigned short* Wob  = (unsigned short*)(ws + 39845888);       // 1024x1024 bf16     2,097,152 B
    float*          q64  = (float*)(ws + 41943040);                // 16384x16 f32       1,048,576 B
    unsigned short* C1   = (unsigned short*)(ws + 42991616);       // 16384x3072 bf16  100,663,296 B

    // fused casts (x->bf16 + q64 dots | Wall build | Wo->bf16)
    k_cast_all<<<dim3(XBLKS + WBLKS), 256, 0, stream>>>(
        x, Wq, Wk, Wv, Wo, xb, Wall, Wob, q64);

    // GEMM1: C1[16384,3072] = xb @ Wall^T (uniform bf16 store) — 768 blocks = 3 rounds
    k_gemm256<0, 0><<<dim3(NW / 256, TOKENS / 256), 512, 0, stream>>>(
        xb, DIM, Wall, DIM, C1, NW, nullptr);

    // gate: one wave per token; q/k softmax + v *= wf * ksm * mask, in place
    k_gate<<<dim3(TOKENS / 4), 256, 0, stream>>>(C1, q64, am);

    // GEMM2: out[16384,1024] = g @ Wo^T + bo  (A = C1 v-section, lda=3072, f32 out)
    k_gemm256<1, 1><<<dim3(DIM / 256, TOKENS / 256), 512, 0, stream>>>(
        C1 + 2048, NW, Wob, DIM, d_out, DIM, bo);
}

// Round 13
// 194.510 us; speedup vs baseline: 1.2075x; 1.2075x over previous
//
#include <hip/hip_runtime.h>
#include <cstdint>

#define TOKENS 16384   // b*l = 4*4096
#define DIM 1024
#define NW 3072        // GEMM1 N: q-slots0-63 (1024) | k (1024) | v (1024) = 12 x 256
#define NKT 16         // K = 1024 = 16 K-tiles of 64

typedef __bf16 bf16_t;
typedef bf16_t bf16x8 __attribute__((ext_vector_type(8)));
typedef unsigned short u16x8 __attribute__((ext_vector_type(8)));
typedef float f32x4 __attribute__((ext_vector_type(4)));

static __device__ __forceinline__ float bf2f(unsigned short u) {
    union { unsigned int i; float f; } v; v.i = ((unsigned int)u) << 16; return v.f;
}
static __device__ __forceinline__ unsigned short f2bf(float f) {
    unsigned int u = __float_as_uint(f);
    unsigned int r = u + 0x7FFFu + ((u >> 16) & 1u);   // RNE
    return (unsigned short)(r >> 16);
}

// async global->LDS, 16B/lane; LDS dest is wave-uniform base + lane*16B (linear).
static __device__ __forceinline__ void gload_lds16(const void* g, void* l) {
    __builtin_amdgcn_global_load_lds(
        (__attribute__((address_space(1))) void*)(uintptr_t)g,
        (__attribute__((address_space(3))) void*)(unsigned int)(uintptr_t)l,
        16, 0, 0);
}

// ---------------- merged cast kernel: x->xb | build Wall | Wq64 | Wo->Wob ----------------
// Wall[3072][1024]: rows [0,1024)=Wq(head h slot s -> h*65+s, s<64), [1024,2048)=Wk, [2048,3072)=Wv
// Wq64[16][1024]: Wq rows h*65+64 (per-head slot-64 projection)
#define XN4    (TOKENS * DIM / 4)           // 4,194,304
#define WALLN4 (NW * DIM / 4)               //   786,432
#define WQ64N4 (16 * DIM / 4)               //     4,096
#define WON4   (DIM * DIM / 4)              //   262,144
#define CASTN4 (XN4 + WALLN4 + WQ64N4 + WON4)
__global__ __launch_bounds__(256) void k_cast_all(const float* __restrict__ x,
                                                  const float* __restrict__ Wq,
                                                  const float* __restrict__ Wk,
                                                  const float* __restrict__ Wv,
                                                  const float* __restrict__ Wo,
                                                  unsigned short* __restrict__ xb,
                                                  unsigned short* __restrict__ Wall,
                                                  unsigned short* __restrict__ Wq64b,
                                                  unsigned short* __restrict__ Wob) {
    int i = blockIdx.x * 256 + threadIdx.x;
    if (i >= CASTN4) return;
    float4 v;
    unsigned short* dst;
    if (i < XN4) {
        v = ((const float4*)x)[i];
        dst = xb + (size_t)i * 4;
    } else if (i < XN4 + WALLN4) {
        int j = i - XN4;
        int c4 = j & 255;          // DIM/4 = 256
        int r  = j >> 8;
        if (r < 1024)            v = ((const float4*)Wq)[((r >> 6) * 65 + (r & 63)) * 256 + c4];
        else if (r < 2048)       v = ((const float4*)Wk)[(r - 1024) * 256 + c4];
        else                     v = ((const float4*)Wv)[(r - 2048) * 256 + c4];
        dst = Wall + (size_t)j * 4;
    } else if (i < XN4 + WALLN4 + WQ64N4) {
        int j = i - XN4 - WALLN4;
        int c4 = j & 255;
        int h  = j >> 8;
        v = ((const float4*)Wq)[(h * 65 + 64) * 256 + c4];
        dst = Wq64b + (size_t)j * 4;
    } else {
        int j = i - XN4 - WALLN4 - WQ64N4;
        v = ((const float4*)Wo)[j];
        dst = Wob + (size_t)j * 4;
    }
    ushort4 o;
    o.x = f2bf(v.x); o.y = f2bf(v.y); o.z = f2bf(v.z); o.w = f2bf(v.w);
    *(ushort4*)dst = o;
}

// ============ 256x256x(BK=64) 8-phase bf16 GEMM: C[M,N] = A[M,K] * Bt[N,K]^T ============
// UNIFORM epilogue — the ONLY stable config (r5/r9/r10/r12: ~107 µs / 94 MB FETCH).
// Any per-kind epilogue divergence costs +60 MB L2 refetch (r6/r8/r11 all refuted).
template<int ADD_BIAS, int OUT_F32>
__global__ __launch_bounds__(512, 2) void k_gemm256(const unsigned short* __restrict__ A, int lda,
                                                    const unsigned short* __restrict__ Bt, int ldb,
                                                    void* __restrict__ Cout, int ldc,
                                                    const float* __restrict__ bias) {
    __shared__ char smem[131072];
    const int tid  = threadIdx.x;
    const int wid  = tid >> 6;          // 0..7
    const int lane = tid & 63;
    const int wm = wid >> 2;            // 0..1  (M half)
    const int wn = wid & 3;             // 0..3  (N quarter)
    const int fr = lane & 15;
    const int fq = lane >> 4;
    const int fr7 = fr & 7;
    const int srow8  = lane >> 3;                        // staging row-in-chunk
    const int cperm8 = ((lane & 7) ^ srow8) * 8;         // staging col perm (elements)

    // XCD-chunked bijective swizzle (nb divisible by 8 for both GEMMs)
    const int nbx = gridDim.x;
    const int nb  = nbx * gridDim.y;
    const int L   = blockIdx.y * nbx + blockIdx.x;
    const int q8  = nb >> 3;
    const int newid = (L & 7) * q8 + (L >> 3);
    const int tm = (newid / nbx) * 256;
    const int tn = (newid % nbx) * 256;

#define STAGE(ptr, ld, tile0, kt2, h, matbase)                                              \
    {                                                                                        \
        _Pragma("unroll")                                                                    \
        for (int j = 0; j < 2; ++j) {                                                        \
            const int c = wid * 2 + j;                                                       \
            const unsigned short* src = (ptr) +                                              \
                (size_t)((tile0) + (h) * 128 + c * 8 + srow8) * (ld) + (kt2) * 64 + cperm8;  \
            char* dst = (char*)smem + ((((kt2) & 1) << 16) | (matbase) | ((h) << 14) | (c << 10)); \
            gload_lds16(src, dst);                                                           \
        }                                                                                    \
    }
#define STAGE_A(kt2, h) STAGE(A, lda, tm, kt2, h, 0)
#define STAGE_B(kt2, h) STAGE(Bt, ldb, tn, kt2, h, 32768)

    const int sx0 = ((0 + fq) ^ fr7) << 4;              // ks=0 16B slot (swizzled)
    const int sx1 = ((4 + fq) ^ fr7) << 4;              // ks=1
    const int aoff = (wm << 14) + (fr << 7);
    const int boff = 32768 + ((wn >> 1) << 14) + ((((wn & 1) * 64) + fr) << 7);

    bf16x8 a[4][2], b0[2][2], b1[2][2];
    f32x4 acc[8][4] = {};

#define READ_A(kb, mh)                                                                       \
    { _Pragma("unroll")                                                                      \
      for (int i = 0; i < 4; ++i) {                                                          \
        a[i][0] = *(const bf16x8*)(smem + (kb) + aoff + (((mh) * 64 + i * 16) << 7) + sx0);  \
        a[i][1] = *(const bf16x8*)(smem + (kb) + aoff + (((mh) * 64 + i * 16) << 7) + sx1);  \
      } }
#define READ_B(kb, nh, breg)                                                                 \
    { _Pragma("unroll")                                                                      \
      for (int n2 = 0; n2 < 2; ++n2) {                                                       \
        breg[n2][0] = *(const bf16x8*)(smem + (kb) + boff + ((((nh) * 2 + n2) * 16) << 7) + sx0); \
        breg[n2][1] = *(const bf16x8*)(smem + (kb) + boff + ((((nh) * 2 + n2) * 16) << 7) + sx1); \
      } }
#define MFMA_Q(mh, nh, breg)                                                                 \
    { _Pragma("unroll")                                                                      \
      for (int i = 0; i < 4; ++i)                                                            \
        _Pragma("unroll")                                                                    \
        for (int n2 = 0; n2 < 2; ++n2) {                                                     \
          acc[(mh) * 4 + i][(nh) * 2 + n2] = __builtin_amdgcn_mfma_f32_16x16x32_bf16(        \
              a[i][0], breg[n2][0], acc[(mh) * 4 + i][(nh) * 2 + n2], 0, 0, 0);              \
          acc[(mh) * 4 + i][(nh) * 2 + n2] = __builtin_amdgcn_mfma_f32_16x16x32_bf16(        \
              a[i][1], breg[n2][1], acc[(mh) * 4 + i][(nh) * 2 + n2], 0, 0, 0);              \
        } }
#define SYNC_PRE()                                             \
    __builtin_amdgcn_s_barrier();                              \
    asm volatile("s_waitcnt lgkmcnt(0)" ::: "memory");         \
    __builtin_amdgcn_sched_barrier(0);                         \
    __builtin_amdgcn_s_setprio(1);
#define SYNC_POST()                                            \
    __builtin_amdgcn_s_setprio(0);                             \
    __builtin_amdgcn_s_barrier();

    // ---- prologue: kt0 fully + kt1's B halves; drain the kt0 stages ----
    STAGE_A(0, 0); STAGE_A(0, 1); STAGE_B(0, 0); STAGE_B(0, 1);
    STAGE_B(1, 0); STAGE_B(1, 1);
    asm volatile("s_waitcnt vmcnt(4)" ::: "memory");
    __builtin_amdgcn_s_barrier();

    for (int kt = 0; kt < NKT; ++kt) {
        const int kb = (kt & 1) << 16;
        // ---- P0 ----
        READ_A(kb, 0);
        READ_B(kb, 0, b0);
        if (kt < NKT - 1) STAGE_A(kt + 1, 0);
        asm volatile("s_waitcnt lgkmcnt(8)" ::: "memory");
        SYNC_PRE(); MFMA_Q(0, 0, b0); SYNC_POST();
        // ---- P1 ----
        READ_B(kb, 1, b1);
        if (kt < NKT - 1) STAGE_A(kt + 1, 1);
        SYNC_PRE(); MFMA_Q(0, 1, b1); SYNC_POST();
        // ---- P2 ----
        READ_A(kb, 1);
        if (kt < NKT - 2) STAGE_B(kt + 2, 0);
        SYNC_PRE(); MFMA_Q(1, 1, b1); SYNC_POST();
        // ---- P3 (no ds_read; uses regs a[mh1], b0) ----
        if (kt < NKT - 2) STAGE_B(kt + 2, 1);
        __builtin_amdgcn_s_barrier();
        __builtin_amdgcn_s_setprio(1); MFMA_Q(1, 0, b0); __builtin_amdgcn_s_setprio(0);
        if (kt < NKT - 2) { asm volatile("s_waitcnt vmcnt(4)" ::: "memory"); }
        else              { asm volatile("s_waitcnt vmcnt(0)" ::: "memory"); }
        __builtin_amdgcn_s_barrier();
    }

    // ---- epilogue: uniform C write ----
#pragma unroll
    for (int mq = 0; mq < 8; ++mq) {
        const int row0 = tm + wm * 128 + mq * 16 + fq * 4;
#pragma unroll
        for (int nf = 0; nf < 4; ++nf) {
            const int col = tn + wn * 64 + nf * 16 + fr;
            f32x4 v = acc[mq][nf];
            const float bb = ADD_BIAS ? bias[col] : 0.0f;
#pragma unroll
            for (int j = 0; j < 4; ++j) {
                const size_t idx = (size_t)(row0 + j) * ldc + col;
                if (OUT_F32) ((float*)Cout)[idx] = v[j] + bb;
                else         ((unsigned short*)Cout)[idx] = f2bf(v[j] + bb);
            }
        }
    }
#undef STAGE
#undef STAGE_A
#undef STAGE_B
#undef READ_A
#undef READ_B
#undef MFMA_Q
#undef SYNC_PRE
#undef SYNC_POST
}

// -------- gate: ONE WAVE PER TOKEN; lane owns 16 consecutive slots, head = aligned
// 4-lane group. Computes q64 in-kernel (r10-verified: its VALU work hides under this
// kernel's memory waits). q-softmax -> wf, k-softmax -> ksm, v-gate, all in-register;
// C1 row = [q 1024 | k 1024 | v 1024], v updated in place. --------
__global__ __launch_bounds__(256) void k_gate(unsigned short* __restrict__ C1,
                                              const unsigned short* __restrict__ xb,
                                              const unsigned short* __restrict__ Wq64,
                                              const float* __restrict__ mask) {
    const int t    = blockIdx.x * 4 + (threadIdx.x >> 6);
    const int lane = threadIdx.x & 63;
    const int h    = lane >> 2;
    unsigned short* row = C1 + (size_t)t * NW;
    const float mk = mask[t];

    // ---- q64[h] = dot(x_row, Wq64[h]) — all 64 lanes cooperate per head (16 elems/lane);
    //      each lane keeps only its own head's value (no runtime-indexed array) ----
    const unsigned short* xrow = xb + (size_t)t * DIM + lane * 16;
    const u16x8 xv0 = *(const u16x8*)(xrow);
    const u16x8 xv1 = *(const u16x8*)(xrow + 8);
    float xf[16];
#pragma unroll
    for (int j = 0; j < 8; ++j) { xf[j] = bf2f(xv0[j]); xf[8 + j] = bf2f(xv1[j]); }
    float myq64 = 0.f;
#pragma unroll
    for (int hh = 0; hh < 16; ++hh) {
        const unsigned short* wrow = Wq64 + (size_t)hh * DIM + lane * 16;
        const u16x8 wv0 = *(const u16x8*)(wrow);
        const u16x8 wv1 = *(const u16x8*)(wrow + 8);
        float d = 0.f;
#pragma unroll
        for (int j = 0; j < 8; ++j)
            d += xf[j] * bf2f(wv0[j]) + xf[8 + j] * bf2f(wv1[j]);
        for (int o = 32; o; o >>= 1) d += __shfl_xor(d, o);
        if (h == hh) myq64 = d;
    }

    // ---- q softmax (64 slots per head across 4 lanes, 16/lane) ----
    const u16x8 q0 = *(const u16x8*)(row + lane * 16);
    const u16x8 q1 = *(const u16x8*)(row + lane * 16 + 8);
    float qf[16];
#pragma unroll
    for (int j = 0; j < 8; ++j) { qf[j] = bf2f(q0[j]); qf[8 + j] = bf2f(q1[j]); }
    float mx = qf[0];
#pragma unroll
    for (int j = 1; j < 16; ++j) mx = fmaxf(mx, qf[j]);
    mx = fmaxf(mx, __shfl_xor(mx, 1));
    mx = fmaxf(mx, __shfl_xor(mx, 2));
    float sm = 0.f;
#pragma unroll
    for (int j = 0; j < 16; ++j) sm += __expf(qf[j] - mx);
    sm += __shfl_xor(sm, 1);
    sm += __shfl_xor(sm, 2);
    const float e64 = __expf(myq64 - mx);
    const float wf = 2.0f * (1.0f - e64 / (sm + e64)) * mk;

    // ---- k softmax ----
    const u16x8 k0 = *(const u16x8*)(row + 1024 + lane * 16);
    const u16x8 k1 = *(const u16x8*)(row + 1024 + lane * 16 + 8);
    float ek[16];
    {
        float kf[16];
#pragma unroll
        for (int j = 0; j < 8; ++j) { kf[j] = bf2f(k0[j]); kf[8 + j] = bf2f(k1[j]); }
        float kmx = kf[0];
#pragma unroll
        for (int j = 1; j < 16; ++j) kmx = fmaxf(kmx, kf[j]);
        kmx = fmaxf(kmx, __shfl_xor(kmx, 1));
        kmx = fmaxf(kmx, __shfl_xor(kmx, 2));
#pragma unroll
        for (int j = 0; j < 16; ++j) ek[j] = __expf(kf[j] - kmx);
    }
    float ks = 0.f;
#pragma unroll
    for (int j = 0; j < 16; ++j) ks += ek[j];
    ks += __shfl_xor(ks, 1);
    ks += __shfl_xor(ks, 2);
    const float f = wf / ks;   // wf * (1/ks); per-slot ksm = ek[j] * (1/ks)

    // ---- gate v in place ----
    const u16x8 v0 = *(const u16x8*)(row + 2048 + lane * 16);
    const u16x8 v1 = *(const u16x8*)(row + 2048 + lane * 16 + 8);
    u16x8 o0, o1;
#pragma unroll
    for (int j = 0; j < 8; ++j) {
        o0[j] = f2bf(f * ek[j]     * bf2f(v0[j]));
        o1[j] = f2bf(f * ek[8 + j] * bf2f(v1[j]));
    }
    *(u16x8*)(row + 2048 + lane * 16)     = o0;
    *(u16x8*)(row + 2048 + lane * 16 + 8) = o1;
}

extern "C" void kernel_launch(void* const* d_in, const int* in_sizes, int n_in,
                              void* d_out, int out_size, void* d_ws, size_t ws_size,
                              hipStream_t stream) {
    (void)in_sizes; (void)n_in; (void)out_size; (void)ws_size;
    const float* x  = (const float*)d_in[0];
    const float* am = (const float*)d_in[1];
    const float* Wq = (const float*)d_in[2];
    const float* Wk = (const float*)d_in[3];
    const float* Wv = (const float*)d_in[4];
    const float* Wo = (const float*)d_in[5];
    const float* bo = (const float*)d_in[6];
    // time_angle / head_time_delta collapse to the constant 2 (see round-0 analysis)

    char* ws = (char*)d_ws;
    unsigned short* xb    = (unsigned short*)(ws);                 // 16384x1024 bf16   33,554,432 B
    unsigned short* Wall  = (unsigned short*)(ws + 33554432);      // 3072x1024 bf16     6,291,456 B
    unsigned short* Wq64b = (unsigned short*)(ws + 39845888);      // 16x1024 bf16          32,768 B
    unsigned short* Wob   = (unsigned short*)(ws + 39878656);      // 1024x1024 bf16     2,097,152 B
    unsigned short* C1    = (unsigned short*)(ws + 41975808);      // 16384x3072 bf16  100,663,296 B

    // fused casts (x->bf16, Wall build, Wq64, Wo->bf16)
    k_cast_all<<<dim3((CASTN4 + 255) / 256), 256, 0, stream>>>(
        x, Wq, Wk, Wv, Wo, xb, Wall, Wq64b, Wob);

    // GEMM1: C1[16384,3072] = xb @ Wall^T (uniform bf16 store) — 768 blocks = 3 rounds
    k_gemm256<0, 0><<<dim3(NW / 256, TOKENS / 256), 512, 0, stream>>>(
        xb, DIM, Wall, DIM, C1, NW, nullptr);

    // gate: one wave per token; q64 dot + q/k softmax + v *= wf * ksm * mask, in place
    k_gate<<<dim3(TOKENS / 4), 256, 0, stream>>>(C1, xb, Wq64b, am);

    // GEMM2: out[16384,1024] = g @ Wo^T + bo  (A = C1 v-section, lda=3072, f32 out)
    k_gemm256<1, 1><<<dim3(DIM / 256, TOKENS / 256), 512, 0, stream>>>(
        C1 + 2048, NW, Wob, DIM, d_out, DIM, bo);
}